// Round 13
// baseline (86.702 us; speedup 1.0000x reference)
//
#include <hip/hip_runtime.h>
#include <stdint.h>

typedef __attribute__((ext_vector_type(8))) __bf16 bf16x8;
typedef __attribute__((ext_vector_type(4))) float f32x4;

// Selected upper-tri circular-adjacency pairs (r,c), row-major triu order. K=64.
__device__ const unsigned char dR[64] = {
  0,0,0,0,0,0,0,
  1,1,1,1,1,1,
  2,2,2,2,2,
  3,3,3,3,
  4,4,4,4,
  5,5,5,5,
  6,6,6,6,
  7,7,7,7,
  8,8,8,8,
  9,9,9,9,
  10,10,10,10,
  11,11,11,11,
  12,12,12,12,
  13,13,13,
  14,14,
  15};
__device__ const unsigned char dC[64] = {
  0,1,2,3,13,14,15,
  1,2,3,4,14,15,
  2,3,4,5,15,
  3,4,5,6,
  4,5,6,7,
  5,6,7,8,
  6,7,8,9,
  7,8,9,10,
  8,9,10,11,
  9,10,11,12,
  10,11,12,13,
  11,12,13,14,
  12,13,14,15,
  13,14,15,
  14,15,
  15};

__device__ __forceinline__ unsigned short f2bf(float x){
  unsigned u = __builtin_bit_cast(unsigned, x);
  return (unsigned short)((u + 0x7FFFu + ((u >> 16) & 1u)) >> 16);
}

// fp32 -> bf16 conversion + K-STEP PACKING: W1 -> [64 ks][512 col][32 k] bf16,
// W2 -> [16 ks][512 col][32 k] bf16. Contiguous 1KB per (ks, 16-col chunk).
__global__ void conv_w_kernel(const float* __restrict__ w1, const float* __restrict__ w2,
                              unsigned short* __restrict__ o1, unsigned short* __restrict__ o2){
  int i = blockIdx.x * 256 + threadIdx.x;
  if (i < 262144){                                  // W1: [512][2048] fp32, float4 idx
    float4 v = ((const float4*)w1)[i];
    ushort4 pk; pk.x=f2bf(v.x); pk.y=f2bf(v.y); pk.z=f2bf(v.z); pk.w=f2bf(v.w);
    const int col = i >> 9;
    const int kb  = (i & 511) << 2;
    const int ks  = kb >> 5, ko = kb & 31;
    ((ushort4*)o1)[(ks << 12) + (col << 3) + (ko >> 2)] = pk;
  } else {
    int j = i - 262144;
    if (j < 65536){                                 // W2: [512][512] fp32
      float4 v = ((const float4*)w2)[j];
      ushort4 pk; pk.x=f2bf(v.x); pk.y=f2bf(v.y); pk.z=f2bf(v.z); pk.w=f2bf(v.w);
      const int col = j >> 7;
      const int kb  = (j & 127) << 2;
      const int ks  = kb >> 5, ko = kb & 31;
      ((ushort4*)o2)[(ks << 12) + (col << 3) + (ko >> 2)] = pk;
    }
  }
}

// LDS: phase 1: gather A dbuf 2x6144 @ 0/6144 ([kb4][96 row][16B]). No W in LDS.
//      phase 2: A1 [96 row][512 h] bf16 XOR-swizzled @ [0, 98304) (aliases, post-barrier)
#define LA0 0
#define LA1 6144

// issue 6 gather register loads into static slot S (parity PAR fixed per slot)
#define GISS(S, PAR, FV) do{ const float* xf_ = xb + ((long)(FV) << 16);                  \
  _Pragma("unroll") for (int o_ = 0; o_ < 3; ++o_)                                        \
  _Pragma("unroll") for (int e_ = 0; e_ < 2; ++e_)                                        \
    g##S[o_][e_] = xf_[poff[PAR][o_][e_]]; }while(0)

// cvt slot -> ds_write A-tile into buffer BUF (compiler inserts counted vmcnt for g regs)
#define CVTWR(S, BUF) do{ _Pragma("unroll") for (int o_ = 0; o_ < 3; ++o_){               \
  unsigned pv_ = (unsigned)f2bf(g##S[o_][0]) | ((unsigned)f2bf(g##S[o_][1]) << 16);       \
  *(unsigned*)(lds + (BUF) + awr + (o_ << 9)) = pv_; } }while(0)

// phase-split K-step: window 1 = issue {4 global W-frag loads (transient regs),
// 6 A-frag ds_reads, 6 gather loads}; bar; lgkm(0) (+ compiler-counted vmcnt for W);
// sched fence (rule #18); window 2 = prio-wrapped 24-MFMA cluster + cvt-write;
// lgkm(0)-only barrier (gathers span it as register loads).
#define PSTEP(ABUF, KSN, GS, GP, GF, CS, CBUF, DO_G, DO_C) do{                            \
  bf16x8 af_[6], bw_[4];                                                                  \
  _Pragma("unroll") for (int cn_ = 0; cn_ < 4; ++cn_)                                     \
    bw_[cn_] = *(const bf16x8*)(w1c + (((long)(KSN)) << 15) + wfo[cn_]);                  \
  _Pragma("unroll") for (int fm_ = 0; fm_ < 6; ++fm_)                                     \
    af_[fm_] = *(const bf16x8*)(lds + (ABUF) + ard + fm_*256);                            \
  if (DO_G) GISS(GS, GP, GF);                                                             \
  __builtin_amdgcn_s_barrier();                                                           \
  asm volatile("s_waitcnt lgkmcnt(0)" ::: "memory");                                      \
  __builtin_amdgcn_sched_barrier(0);                                                      \
  __builtin_amdgcn_s_setprio(1);                                                          \
  _Pragma("unroll") for (int cn_ = 0; cn_ < 4; ++cn_)                                     \
  _Pragma("unroll") for (int fm_ = 0; fm_ < 6; ++fm_)                                     \
    acc[fm_][cn_] = __builtin_amdgcn_mfma_f32_16x16x32_bf16(af_[fm_], bw_[cn_], acc[fm_][cn_], 0, 0, 0); \
  __builtin_amdgcn_s_setprio(0);                                                          \
  if (DO_C) CVTWR(CS, CBUF);                                                              \
  asm volatile("s_waitcnt lgkmcnt(0)" ::: "memory");                                      \
  __builtin_amdgcn_s_barrier();                                                           \
  asm volatile("" ::: "memory");                                                          \
}while(0)

#define A2SUB(ss, cc) do{                                                                 \
  bf16x8 a2[6];                                                                           \
  _Pragma("unroll") for (int fm = 0; fm < 6; ++fm){                                       \
    int byt = (((fm << 4) + lr) << 10) + ((ss) << 6) + (q << 4);                          \
    byt ^= (lr & 7) << 4;                                                                 \
    a2[fm] = *(const bf16x8*)(lds + byt);                                                 \
  }                                                                                       \
  _Pragma("unroll") for (int cn = 0; cn < 4; ++cn)                                        \
    _Pragma("unroll") for (int fm = 0; fm < 6; ++fm)                                      \
      acc2[fm][cn] = __builtin_amdgcn_mfma_f32_16x16x32_bf16(a2[fm], cc[cn], acc2[fm][cn], 0, 0, 0); \
}while(0)

// Block = (b, 32-t tile): 256 blocks, 512 threads (8 waves). Each wave: [96m x 64n].
__global__ __launch_bounds__(512, 2)
void fused_kernel(const float* __restrict__ x,
                  const float* __restrict__ b1v,
                  const float* __restrict__ b2v,
                  const unsigned short* __restrict__ w1b,
                  const unsigned short* __restrict__ w2b,
                  float* __restrict__ out)
{
  __shared__ char lds[98304];
  const int bid = blockIdx.x;
  const int b   = bid >> 3;
  const int t0  = (bid & 7) << 5;

  const int tid  = threadIdx.x;
  const int w    = tid >> 6;
  const int lane = tid & 63;
  const int q    = lane >> 4;
  const int lr   = lane & 15;
  const int u    = tid >> 5;          // [0,16): k-pair index for gather
  const int tt   = tid & 31;          // t within tile for gather

  // gather source offsets: k = par*32 + 2u + e
  int poff[2][3][2];
#pragma unroll
  for (int par = 0; par < 2; ++par)
#pragma unroll
    for (int e = 0; e < 2; ++e){
      const int k = par * 32 + 2 * u + e;
      const int r = dR[k], c = dC[k];
#pragma unroll
      for (int o = 0; o < 3; ++o){
        const int v = o - 1;                         // mean over o is order-free
        poff[par][o][e] = ((((r - v) & 15) << 4) | ((c - v) & 15)) << 8;
      }
    }
  const float* xb = x + (((long)b << 21) + t0 + tt);

  // A-tile: [kb4][row96][16B], kb stride 1536
  const int awr = ((u >> 2) * 1536) + (tt << 4) + ((u & 3) << 2);   // + o*512
  const int ard = q * 1536 + (lr << 4);                              // + fm*256
  // W1 fragment offsets into packed [ks][512 col][32 k] (direct L2, 1KB/16-col chunk)
  const char* w1c = (const char*)w1b;
  int wfo[4];
  float b1c[4];
#pragma unroll
  for (int cn = 0; cn < 4; ++cn){
    const int col = (w << 6) + (cn << 4) + lr;
    wfo[cn] = (col << 6) + (q << 4);
    b1c[cn] = b1v[col];
  }

  f32x4 acc[6][4];
#pragma unroll
  for (int fm = 0; fm < 6; ++fm)
#pragma unroll
    for (int cn = 0; cn < 4; ++cn)
      acc[fm][cn] = f32x4{0.f, 0.f, 0.f, 0.f};

  float g0[3][2], g1[3][2];

  // ---------------- prologue ----------------
  // tile0 -> LA0 directly; g1 <- tile1 in flight; lgkm-only barrier.
  {
    float gp[3][2];
#pragma unroll
    for (int o_ = 0; o_ < 3; ++o_)
#pragma unroll
      for (int e_ = 0; e_ < 2; ++e_)
        gp[o_][e_] = xb[poff[0][o_][e_]];          // tile 0 (f=0, par=0)
    GISS(1, 1, 0);                                 // tile 1 (f=0, par=1)
#pragma unroll
    for (int o_ = 0; o_ < 3; ++o_){
      unsigned pv_ = (unsigned)f2bf(gp[o_][0]) | ((unsigned)f2bf(gp[o_][1]) << 16);
      *(unsigned*)(lds + LA0 + awr + (o_ << 9)) = pv_;
    }
    asm volatile("s_waitcnt lgkmcnt(0)" ::: "memory");
    __builtin_amdgcn_s_barrier();
    asm volatile("" ::: "memory");
  }

  // ---------------- phase 1: 64 K-steps, double-barrier phase schedule ----------
  // step N: W frags ks=N direct from L2 (transient regs); A from LA[N%2];
  //         issue gather tile N+2 (slot N%2); MFMA; cvt tile N+1 -> LA[(N+1)%2].
#pragma unroll 1
  for (int it = 0; it < 31; ++it){
    PSTEP(LA0, (it << 1),     0, 0, it + 1, 1, LA1, 1, 1);   // even step 2it
    PSTEP(LA1, (it << 1) + 1, 1, 1, it + 1, 0, LA0, 1, 1);   // odd step 2it+1
  }
  PSTEP(LA0, 62, 0, 0, 0, 1, LA1, 0, 1);   // step 62: cvt tile 63 (slot g1)
  PSTEP(LA1, 63, 0, 0, 0, 0, LA0, 0, 0);   // step 63: compute only

  // ---------------- epilogue 1: bias + leaky -> A1 bf16 (XOR-swizzled) --------
#pragma unroll
  for (int cn = 0; cn < 4; ++cn){
    const int h  = (w << 6) + (cn << 4) + lr;
#pragma unroll
    for (int fm = 0; fm < 6; ++fm)
#pragma unroll
      for (int r = 0; r < 4; ++r){
        float vv = acc[fm][cn][r] + b1c[cn];
        vv = vv > 0.f ? vv : 0.01f * vv;
        const int row = (fm << 4) + (q << 2) + r;    // D row = 4*(lane>>4)+reg
        int byt = (row << 10) + (h << 1);
        byt ^= (row & 7) << 4;
        *(unsigned short*)(lds + byt) = f2bf(vv);
      }
  }
  asm volatile("s_waitcnt lgkmcnt(0)" ::: "memory");
  __builtin_amdgcn_s_barrier();
  asm volatile("" ::: "memory");

  // ---------------- phase 2: K=512 vs packed W2 (L2 reg frags), barrier-free ----
  int w2off[4];
  float b2c[4];
#pragma unroll
  for (int cn = 0; cn < 4; ++cn){
    const int col = (w << 6) + (cn << 4) + lr;
    w2off[cn] = (col << 6) + (q << 4);
    b2c[cn] = b2v[col];
  }
  const char* w2c = (const char*)w2b;
  f32x4 acc2[6][4];
#pragma unroll
  for (int fm = 0; fm < 6; ++fm)
#pragma unroll
    for (int cn = 0; cn < 4; ++cn)
      acc2[fm][cn] = f32x4{0.f, 0.f, 0.f, 0.f};

  bf16x8 c0[4], c1[4];
#pragma unroll
  for (int cn = 0; cn < 4; ++cn) c0[cn] = *(const bf16x8*)(w2c + w2off[cn]);

#pragma unroll 1
  for (int it2 = 0; it2 < 8; ++it2){
    const int s0 = it2 << 1;
#pragma unroll
    for (int cn = 0; cn < 4; ++cn)
      c1[cn] = *(const bf16x8*)(w2c + (((long)(s0 + 1)) << 15) + w2off[cn]);
    A2SUB(s0, c0);
    if (it2 < 7){
#pragma unroll
      for (int cn = 0; cn < 4; ++cn)
        c0[cn] = *(const bf16x8*)(w2c + (((long)(s0 + 2)) << 15) + w2off[cn]);
    }
    A2SUB(s0 + 1, c1);
  }

  // ---------------- epilogue 2: bias + leaky + mean(o) -> [B,H,T] -------------
#pragma unroll
  for (int cn = 0; cn < 4; ++cn){
    const int h  = (w << 6) + (cn << 4) + lr;
#pragma unroll
    for (int p = 0; p < 2; ++p){
      f32x4 ov;
#pragma unroll
      for (int r = 0; r < 4; ++r){
        float s = 0.f;
#pragma unroll
        for (int oo = 0; oo < 3; ++oo){
          float vv = acc2[oo * 2 + p][cn][r] + b2c[cn];
          vv = vv > 0.f ? vv : 0.01f * vv;
          s += vv;
        }
        ov[r] = s * (1.f / 3.f);
      }
      *(f32x4*)(out + (((long)b * 512 + h) << 8) + t0 + (p << 4) + (q << 2)) = ov;
    }
  }
}

extern "C" void kernel_launch(void* const* d_in, const int* in_sizes, int n_in,
                              void* d_out, int out_size, void* d_ws, size_t ws_size,
                              hipStream_t stream){
  const float* x  = (const float*)d_in[0];
  const float* w1 = (const float*)d_in[1];
  const float* b1 = (const float*)d_in[2];
  const float* w2 = (const float*)d_in[3];
  const float* b2 = (const float*)d_in[4];
  unsigned short* w1b = (unsigned short*)d_ws;            // packed W1: 2 MiB
  unsigned short* w2b = w1b + 512 * 2048;                 // packed W2: 0.5 MiB
  conv_w_kernel<<<1280, 256, 0, stream>>>(w1, w2, w1b, w2b);
  fused_kernel<<<256, 512, 0, stream>>>(x, b1, b2, w1b, w2b, (float*)d_out);
}